// Round 1
// baseline (232.023 us; speedup 1.0000x reference)
//
#include <hip/hip_runtime.h>
#include <hip/hip_bf16.h>

// Problem constants
#define Bv 32
#define Dv 512
#define Kv 64
#define Nv 1024
#define EPSv 1e-12f

// ---------------------------------------------------------------------------
// Kernel A: scores = conv_w @ x[b]  (K x N per b), softmax over K, write
// assign, atomicAdd per-(b,k) column sums into asum.
// Block: 256 threads, computes full K=64 x 64-column tile -> softmax in-block.
// Grid: (N/64, B) = (16, 32) = 512 blocks.
// ---------------------------------------------------------------------------
__global__ __launch_bounds__(256) void score_softmax_assign(
    const float* __restrict__ x, const float* __restrict__ w,
    float* __restrict__ assign, float* __restrict__ asum) {
  __shared__ float sh[4160];      // GEMM stage: ws[32][65] + xs[32][65]; then scores s[64][65]
  __shared__ float red[4][64];
  __shared__ float scol[64];

  float* ws = sh;                 // [dl][kl] transposed w tile, row stride 65
  float* xs = sh + 32 * 65;       // [dl][nl] x tile, row stride 65

  const int t = threadIdx.x;
  const int b = blockIdx.y;
  const int n0 = blockIdx.x * 64;
  const int tx = t & 15, ty = t >> 4;

  float acc[4][4];
#pragma unroll
  for (int i = 0; i < 4; i++)
#pragma unroll
    for (int j = 0; j < 4; j++) acc[i][j] = 0.f;

  const float* xb = x + (size_t)b * Dv * Nv + n0;

  for (int d0 = 0; d0 < Dv; d0 += 32) {
    // stage w tile (64k x 32d -> ws[dl][kl]) and x tile (32d x 64n -> xs[dl][nl])
#pragma unroll
    for (int r = 0; r < 8; r++) {
      int idx = r * 256 + t;
      int kl = idx >> 5, dl = idx & 31;
      ws[dl * 65 + kl] = w[kl * Dv + d0 + dl];
      int dl2 = idx >> 6, nl = idx & 63;
      xs[dl2 * 65 + nl] = xb[(size_t)(d0 + dl2) * Nv + nl];
    }
    __syncthreads();
#pragma unroll
    for (int dl = 0; dl < 32; dl++) {
      float wv[4], xv[4];
#pragma unroll
      for (int i = 0; i < 4; i++) wv[i] = ws[dl * 65 + ty * 4 + i];
#pragma unroll
      for (int j = 0; j < 4; j++) xv[j] = xs[dl * 65 + tx * 4 + j];
#pragma unroll
      for (int i = 0; i < 4; i++)
#pragma unroll
        for (int j = 0; j < 4; j++) acc[i][j] = fmaf(wv[i], xv[j], acc[i][j]);
    }
    __syncthreads();
  }

  // scores tile -> LDS s[64][65]  (k = ty*4+i, local col = tx*4+j)
  float* s = sh;
#pragma unroll
  for (int i = 0; i < 4; i++)
#pragma unroll
    for (int j = 0; j < 4; j++) s[(ty * 4 + i) * 65 + tx * 4 + j] = acc[i][j];
  __syncthreads();

  // softmax over k (64) for each of the 64 local columns; 4 threads per column
  const int c = t & 63;   // column
  const int q = t >> 6;   // quarter of k-range
  float m = -1e30f;
#pragma unroll
  for (int kk = 0; kk < 16; kk++) m = fmaxf(m, s[(q * 16 + kk) * 65 + c]);
  red[q][c] = m;
  __syncthreads();
  float mcol = fmaxf(fmaxf(red[0][c], red[1][c]), fmaxf(red[2][c], red[3][c]));
  float ps = 0.f;
#pragma unroll
  for (int kk = 0; kk < 16; kk++) {
    float e = __expf(s[(q * 16 + kk) * 65 + c] - mcol);
    s[(q * 16 + kk) * 65 + c] = e;
    ps += e;
  }
  __syncthreads();             // all reads of red (mcol) complete before overwrite
  red[q][c] = ps;
  __syncthreads();
  float sum = red[0][c] + red[1][c] + red[2][c] + red[3][c];
  if (q == 0) scol[c] = 1.0f / sum;
  __syncthreads();

  // per-(b,k) partial column sums -> atomicAdd
  if (t < 64) {
    float sk = 0.f;
#pragma unroll
    for (int c2 = 0; c2 < 64; c2++) sk += s[t * 65 + c2] * scol[c2];
    atomicAdd(&asum[(size_t)b * Kv + t], sk);
  }

  // write assign[b][k][n0+cc]
  float* ab = assign + (size_t)b * Kv * Nv + n0;
#pragma unroll
  for (int r2 = 0; r2 < 16; r2++) {
    int idx = r2 * 256 + t;
    int k = idx >> 6, cc = idx & 63;
    ab[(size_t)k * Nv + cc] = s[k * 65 + cc] * scol[cc];
  }
}

// ---------------------------------------------------------------------------
// Kernel B: vlad[b,d,k] = sum_n x[b,d,n]*assign[b,k,n] - centers[d,k]*asum[b,k]
// Block: 256 threads, 64d x 64k tile, 4x4 microtile. Grid: (D/64, B) = (8,32).
// ---------------------------------------------------------------------------
__global__ __launch_bounds__(256) void vlad_gemm(
    const float* __restrict__ x, const float* __restrict__ assign,
    const float* __restrict__ centers, const float* __restrict__ asum,
    float* __restrict__ vlad) {
  __shared__ float xs[32][65];   // [nl][dl]
  __shared__ float as_[32][65];  // [nl][kl]
  const int t = threadIdx.x;
  const int b = blockIdx.y;
  const int d0 = blockIdx.x * 64;
  const int tx = t & 15, ty = t >> 4;

  float acc[4][4];
#pragma unroll
  for (int i = 0; i < 4; i++)
#pragma unroll
    for (int j = 0; j < 4; j++) acc[i][j] = 0.f;

  const float* xb = x + ((size_t)b * Dv + d0) * Nv;
  const float* ab = assign + (size_t)b * Kv * Nv;

  for (int n0 = 0; n0 < Nv; n0 += 32) {
#pragma unroll
    for (int r = 0; r < 8; r++) {
      int idx = r * 256 + t;          // 0..2047
      int row = idx >> 5, nl = idx & 31;
      xs[nl][row] = xb[(size_t)row * Nv + n0 + nl];
      as_[nl][row] = ab[(size_t)row * Nv + n0 + nl];
    }
    __syncthreads();
#pragma unroll
    for (int nl = 0; nl < 32; nl++) {
      float xv[4], av[4];
#pragma unroll
      for (int i = 0; i < 4; i++) xv[i] = xs[nl][ty * 4 + i];
#pragma unroll
      for (int j = 0; j < 4; j++) av[j] = as_[nl][tx * 4 + j];
#pragma unroll
      for (int i = 0; i < 4; i++)
#pragma unroll
        for (int j = 0; j < 4; j++) acc[i][j] = fmaf(xv[i], av[j], acc[i][j]);
    }
    __syncthreads();
  }

#pragma unroll
  for (int i = 0; i < 4; i++) {
    int d = d0 + ty * 4 + i;
#pragma unroll
    for (int j = 0; j < 4; j++) {
      int k = tx * 4 + j;
      float v = acc[i][j] - centers[d * Kv + k] * asum[(size_t)b * Kv + k];
      vlad[((size_t)b * Dv + d) * Kv + k] = v;
    }
  }
}

// ---------------------------------------------------------------------------
// Kernel C: per-(b,k) column L2 norm over d -> colscale; per-b global scale.
// One block per b.
// ---------------------------------------------------------------------------
__global__ __launch_bounds__(256) void colnorm_kernel(
    const float* __restrict__ vlad, float* __restrict__ colscale,
    float* __restrict__ bscale) {
  const int b = blockIdx.x;
  const int t = threadIdx.x;
  const int k = t & 63, r = t >> 6;
  const float* vb = vlad + (size_t)b * Dv * Kv;
  float ss = 0.f;
  for (int d = r; d < Dv; d += 4) {
    float v = vb[(size_t)d * Kv + k];
    ss = fmaf(v, v, ss);
  }
  __shared__ float part[4][64];
  __shared__ float contrib[64];
  part[r][k] = ss;
  __syncthreads();
  if (t < 64) {
    float tot = part[0][t] + part[1][t] + part[2][t] + part[3][t];
    float sc = 1.0f / fmaxf(sqrtf(tot), EPSv);
    colscale[(size_t)b * Kv + t] = sc;
    contrib[t] = tot * sc * sc;
  }
  __syncthreads();
  if (t == 0) {
    float tot = 0.f;
#pragma unroll
    for (int i = 0; i < 64; i++) tot += contrib[i];
    bscale[b] = 1.0f / fmaxf(sqrtf(tot), EPSv);
  }
}

// ---------------------------------------------------------------------------
// Kernel D: out[b,d*K+k] = vlad[b,d,k] * colscale[b,k] * bscale[b]
// ---------------------------------------------------------------------------
__global__ __launch_bounds__(256) void scale_kernel(
    const float* __restrict__ vlad, const float* __restrict__ colscale,
    const float* __restrict__ bscale, float* __restrict__ out) {
  size_t i = (size_t)blockIdx.x * 256 + threadIdx.x;  // over B*D*K
  int k = (int)(i & 63);
  size_t bd = i >> 6;
  int b = (int)(bd >> 9);  // /512
  out[i] = vlad[i] * colscale[(size_t)b * 64 + k] * bscale[b];
}

extern "C" void kernel_launch(void* const* d_in, const int* in_sizes, int n_in,
                              void* d_out, int out_size, void* d_ws, size_t ws_size,
                              hipStream_t stream) {
  const float* x = (const float*)d_in[0];        // [B, D, N]
  const float* w = (const float*)d_in[1];        // [K, D]
  const float* centers = (const float*)d_in[2];  // [D, K]
  float* out = (float*)d_out;                    // [B, D*K]

  float* assign = (float*)d_ws;                  // B*K*N = 2097152
  float* vlad = assign + (size_t)Bv * Kv * Nv;   // B*D*K = 1048576
  float* asum = vlad + (size_t)Bv * Dv * Kv;     // B*K = 2048
  float* colscale = asum + Bv * Kv;              // B*K = 2048
  float* bscale = colscale + Bv * Kv;            // B = 32

  hipMemsetAsync(asum, 0, (size_t)Bv * Kv * sizeof(float), stream);

  score_softmax_assign<<<dim3(Nv / 64, Bv), 256, 0, stream>>>(x, w, assign, asum);
  vlad_gemm<<<dim3(Dv / 64, Bv), 256, 0, stream>>>(x, assign, centers, asum, vlad);
  colnorm_kernel<<<Bv, 256, 0, stream>>>(vlad, colscale, bscale);
  scale_kernel<<<(Bv * Dv * Kv) / 256, 256, 0, stream>>>(vlad, colscale, bscale, out);
}

// Round 2
// 173.105 us; speedup vs baseline: 1.3404x; 1.3404x over previous
//
#include <hip/hip_runtime.h>
#include <hip/hip_bf16.h>

#define Bv 32
#define Dv 512
#define Kv 64
#define Nv 1024
#define EPSv 1e-12f

typedef __attribute__((ext_vector_type(8))) short bf16x8;
typedef __attribute__((ext_vector_type(4))) float f32x4;

// fp32 -> bf16 (RNE), bit-level
__device__ __forceinline__ unsigned short f2b(float f) {
  union { float f; unsigned u; } v; v.f = f;
  unsigned r = v.u + 0x7fffu + ((v.u >> 16) & 1u);
  return (unsigned short)(r >> 16);
}

// ---------------------------------------------------------------------------
// Kernel A: scores = conv_w @ x[b] (64k x 64n tile) via bf16 MFMA, softmax
// over k in-block, write assign (bf16) + asum (fp32 atomics).
// Grid (N/64, B) = (16, 32), 256 threads (4 waves).
// Wave wv owns k-rows [wv*16, wv*16+16), all 64 n (4 MFMA tiles).
// ---------------------------------------------------------------------------
__global__ __launch_bounds__(256) void score_softmax_assign(
    const float* __restrict__ x, const float* __restrict__ w,
    unsigned short* __restrict__ assign, float* __restrict__ asum) {
  __shared__ unsigned short xs[32 * 68];  // [d-local][n-local], pad 68
  __shared__ float s[64 * 65];            // scores [k][n], pad 65
  __shared__ float red[4][64];
  __shared__ float scol[64];

  const int t = threadIdx.x;
  const int b = blockIdx.y;
  const int n0 = blockIdx.x * 64;
  const int wv = t >> 6;
  const int lane = t & 63;
  const int q = lane >> 4;
  const int m = lane & 15;

  f32x4 acc[4];
#pragma unroll
  for (int i = 0; i < 4; i++) acc[i] = (f32x4){0.f, 0.f, 0.f, 0.f};

  const float* xb = x + (size_t)b * Dv * Nv + n0;

  for (int d0 = 0; d0 < Dv; d0 += 32) {
    // stage x tile [32 d][64 n] as bf16 into LDS (coalesced float2 reads)
#pragma unroll
    for (int r = 0; r < 4; r++) {
      int u = r * 256 + t;              // 0..1023 over 32d x 32 n-pairs
      int dl = u >> 5;
      int np = (u & 31) * 2;
      float2 v = *(const float2*)&xb[(size_t)(d0 + dl) * Nv + np];
      unsigned pack = (unsigned)f2b(v.x) | ((unsigned)f2b(v.y) << 16);
      *(unsigned*)&xs[dl * 68 + np] = pack;
    }
    __syncthreads();

    // A-frag: w[k0+m][d0 + q*8 + j], contiguous in d -> 2x float4 + cvt
    const float* wp = w + (size_t)(wv * 16 + m) * Dv + d0 + q * 8;
    float4 wa = *(const float4*)wp;
    float4 wbv = *(const float4*)(wp + 4);
    bf16x8 af;
    af[0] = (short)f2b(wa.x); af[1] = (short)f2b(wa.y);
    af[2] = (short)f2b(wa.z); af[3] = (short)f2b(wa.w);
    af[4] = (short)f2b(wbv.x); af[5] = (short)f2b(wbv.y);
    af[6] = (short)f2b(wbv.z); af[7] = (short)f2b(wbv.w);

#pragma unroll
    for (int ns = 0; ns < 4; ns++) {
      bf16x8 bfv;
#pragma unroll
      for (int j = 0; j < 8; j++)
        bfv[j] = (short)xs[(q * 8 + j) * 68 + ns * 16 + m];
      acc[ns] = __builtin_amdgcn_mfma_f32_16x16x32_bf16(af, bfv, acc[ns], 0, 0, 0);
    }
    __syncthreads();
  }

  // scores -> LDS: D layout col=lane&15, row=(lane>>4)*4+r
#pragma unroll
  for (int ns = 0; ns < 4; ns++)
#pragma unroll
    for (int r = 0; r < 4; r++)
      s[(wv * 16 + q * 4 + r) * 65 + ns * 16 + m] = acc[ns][r];
  __syncthreads();

  // softmax over k (64) per column; 4 threads per column
  const int c = t & 63;
  const int qq = t >> 6;
  float mx = -1e30f;
#pragma unroll
  for (int kk = 0; kk < 16; kk++) mx = fmaxf(mx, s[(qq * 16 + kk) * 65 + c]);
  red[qq][c] = mx;
  __syncthreads();
  float mcol = fmaxf(fmaxf(red[0][c], red[1][c]), fmaxf(red[2][c], red[3][c]));
  float ps = 0.f;
#pragma unroll
  for (int kk = 0; kk < 16; kk++) {
    float e = __expf(s[(qq * 16 + kk) * 65 + c] - mcol);
    s[(qq * 16 + kk) * 65 + c] = e;
    ps += e;
  }
  __syncthreads();
  red[qq][c] = ps;
  __syncthreads();
  float sum = red[0][c] + red[1][c] + red[2][c] + red[3][c];
  if (qq == 0) scol[c] = 1.0f / sum;
  __syncthreads();

  // per-(b,k) column sums -> atomicAdd (fp32, pre-quantization values)
  if (t < 64) {
    float sk = 0.f;
#pragma unroll
    for (int c2 = 0; c2 < 64; c2++) sk += s[t * 65 + c2] * scol[c2];
    atomicAdd(&asum[b * Kv + t], sk);
  }

  // write assign as bf16 (packed pairs, coalesced)
  unsigned short* ab = assign + (size_t)b * Kv * Nv + n0;
#pragma unroll
  for (int r2 = 0; r2 < 8; r2++) {
    int idx = r2 * 256 + t;            // 0..2047 over 64k x 32 n-pairs
    int k = idx >> 5;
    int np = (idx & 31) * 2;
    unsigned pack = (unsigned)f2b(s[k * 65 + np] * scol[np]) |
                    ((unsigned)f2b(s[k * 65 + np + 1] * scol[np + 1]) << 16);
    *(unsigned*)&ab[(size_t)k * Nv + np] = pack;
  }
}

// ---------------------------------------------------------------------------
// Kernel B: vlad[b,d,k] = sum_n x*assign - centers*asum via bf16 MFMA.
// LDS-free: both fragments are 16B-per-lane contiguous global loads.
// Grid (D/32, B) = (16, 32), 256 threads. Wave wv: dsub=wv&1, ksubs=(wv>>1)*2+{0,1}.
// ---------------------------------------------------------------------------
__global__ __launch_bounds__(256) void vlad_mfma(
    const float* __restrict__ x, const unsigned short* __restrict__ assign,
    const float* __restrict__ centers, const float* __restrict__ asum,
    float* __restrict__ vlad) {
  const int t = threadIdx.x;
  const int b = blockIdx.y;
  const int d0 = blockIdx.x * 32;
  const int wv = t >> 6;
  const int lane = t & 63;
  const int q = lane >> 4;
  const int m = lane & 15;
  const int dsub = wv & 1;
  const int ks0 = (wv >> 1) * 2;

  f32x4 acc0 = {0.f, 0.f, 0.f, 0.f};
  f32x4 acc1 = {0.f, 0.f, 0.f, 0.f};

  const int drow = d0 + dsub * 16 + m;
  const float* xp = x + ((size_t)b * Dv + drow) * Nv + q * 8;
  const unsigned short* bp0 = assign + ((size_t)b * Kv + ks0 * 16 + m) * Nv + q * 8;
  const unsigned short* bp1 = bp0 + 16 * Nv;

#pragma unroll 4
  for (int n0 = 0; n0 < Nv; n0 += 32) {
    float4 xa = *(const float4*)(xp + n0);
    float4 xc = *(const float4*)(xp + n0 + 4);
    bf16x8 af;
    af[0] = (short)f2b(xa.x); af[1] = (short)f2b(xa.y);
    af[2] = (short)f2b(xa.z); af[3] = (short)f2b(xa.w);
    af[4] = (short)f2b(xc.x); af[5] = (short)f2b(xc.y);
    af[6] = (short)f2b(xc.z); af[7] = (short)f2b(xc.w);
    bf16x8 bf0 = *(const bf16x8*)(bp0 + n0);
    bf16x8 bf1 = *(const bf16x8*)(bp1 + n0);
    acc0 = __builtin_amdgcn_mfma_f32_16x16x32_bf16(af, bf0, acc0, 0, 0, 0);
    acc1 = __builtin_amdgcn_mfma_f32_16x16x32_bf16(af, bf1, acc1, 0, 0, 0);
  }

  const float as0 = asum[b * Kv + ks0 * 16 + m];
  const float as1 = asum[b * Kv + ks0 * 16 + 16 + m];
#pragma unroll
  for (int r = 0; r < 4; r++) {
    int d = d0 + dsub * 16 + q * 4 + r;
    int k0i = ks0 * 16 + m;
    int k1i = k0i + 16;
    vlad[((size_t)b * Dv + d) * Kv + k0i] = acc0[r] - centers[d * Kv + k0i] * as0;
    vlad[((size_t)b * Dv + d) * Kv + k1i] = acc1[r] - centers[d * Kv + k1i] * as1;
  }
}

// ---------------------------------------------------------------------------
// Kernel C1: partial sum of squares over d-range per (b,k) -> atomicAdd.
// Grid (D/64, B) = (8, 32).
// ---------------------------------------------------------------------------
__global__ __launch_bounds__(256) void colsq_partial(
    const float* __restrict__ vlad, float* __restrict__ colsq) {
  const int b = blockIdx.y;
  const int d0 = blockIdx.x * 64;
  const int t = threadIdx.x;
  const int k = t & 63, r = t >> 6;
  const float* vb = vlad + ((size_t)b * Dv + d0) * Kv;
  float ss = 0.f;
#pragma unroll
  for (int dd = r; dd < 64; dd += 4) {
    float v = vb[(size_t)dd * Kv + k];
    ss = fmaf(v, v, ss);
  }
  __shared__ float part[4][64];
  part[r][k] = ss;
  __syncthreads();
  if (t < 64)
    atomicAdd(&colsq[b * Kv + t], part[0][t] + part[1][t] + part[2][t] + part[3][t]);
}

// ---------------------------------------------------------------------------
// Kernel C2: colscale + bscale per b. 32 blocks x 64 threads (1 wave).
// ---------------------------------------------------------------------------
__global__ __launch_bounds__(64) void finalize_scales(
    const float* __restrict__ colsq, float* __restrict__ colscale,
    float* __restrict__ bscale) {
  const int b = blockIdx.x;
  const int k = threadIdx.x;
  float tot = colsq[b * Kv + k];
  float sc = 1.0f / fmaxf(sqrtf(tot), EPSv);
  colscale[b * Kv + k] = sc;
  float contrib = tot * sc * sc;
#pragma unroll
  for (int off = 32; off > 0; off >>= 1) contrib += __shfl_down(contrib, off);
  if (k == 0) bscale[b] = 1.0f / fmaxf(sqrtf(contrib), EPSv);
}

// ---------------------------------------------------------------------------
// Kernel D: out = vlad * colscale[b,k] * bscale[b]
// ---------------------------------------------------------------------------
__global__ __launch_bounds__(256) void scale_kernel(
    const float* __restrict__ vlad, const float* __restrict__ colscale,
    const float* __restrict__ bscale, float* __restrict__ out) {
  size_t i = (size_t)blockIdx.x * 256 + threadIdx.x;  // over B*D*K
  int k = (int)(i & 63);
  size_t bd = i >> 6;
  int b = (int)(bd >> 9);
  out[i] = vlad[i] * colscale[(size_t)b * 64 + k] * bscale[b];
}

extern "C" void kernel_launch(void* const* d_in, const int* in_sizes, int n_in,
                              void* d_out, int out_size, void* d_ws, size_t ws_size,
                              hipStream_t stream) {
  const float* x = (const float*)d_in[0];        // [B, D, N]
  const float* w = (const float*)d_in[1];        // [K, D]
  const float* centers = (const float*)d_in[2];  // [D, K]
  float* out = (float*)d_out;                    // [B, D*K]

  char* ws = (char*)d_ws;
  unsigned short* assign = (unsigned short*)ws;               // B*K*N bf16 = 4 MB
  float* vlad = (float*)(ws + 4194304);                       // B*D*K fp32 = 4 MB
  float* asum = (float*)(ws + 8388608);                       // B*K
  float* colsq = asum + Bv * Kv;                              // B*K (contiguous w/ asum)
  float* colscale = colsq + Bv * Kv;                          // B*K
  float* bscale = colscale + Bv * Kv;                         // B

  // zero asum + colsq in one memset (contiguous)
  hipMemsetAsync(asum, 0, (size_t)2 * Bv * Kv * sizeof(float), stream);

  score_softmax_assign<<<dim3(Nv / 64, Bv), 256, 0, stream>>>(x, w, assign, asum);
  vlad_mfma<<<dim3(Dv / 32, Bv), 256, 0, stream>>>(x, assign, centers, asum, vlad);
  colsq_partial<<<dim3(Dv / 64, Bv), 256, 0, stream>>>(vlad, colsq);
  finalize_scales<<<Bv, 64, 0, stream>>>(colsq, colscale, bscale);
  scale_kernel<<<(Bv * Dv * Kv) / 256, 256, 0, stream>>>(vlad, colscale, bscale, out);
}

// Round 3
// 164.834 us; speedup vs baseline: 1.4076x; 1.0502x over previous
//
#include <hip/hip_runtime.h>
#include <hip/hip_bf16.h>

#define Bv 32
#define Dv 512
#define Kv 64
#define Nv 1024
#define EPSv 1e-12f

typedef __attribute__((ext_vector_type(8))) short bf16x8;
typedef __attribute__((ext_vector_type(4))) float f32x4;

// fp32 -> bf16 (RNE), bit-level
__device__ __forceinline__ unsigned short f2b(float f) {
  union { float f; unsigned u; } v; v.f = f;
  unsigned r = v.u + 0x7fffu + ((v.u >> 16) & 1u);
  return (unsigned short)(r >> 16);
}

// ---------------------------------------------------------------------------
// Kernel A: scores = conv_w @ x[b] (64k x 32n tile) via bf16 MFMA with
// DIRECT global loads (no LDS staging, no barriers in GEMM phase), softmax
// over k in-block, write assign (bf16) + asum (fp32 atomics).
// Grid (N/32, B) = (32, 32) = 1024 blocks, 256 threads.
// Wave wv owns k-rows [wv*16, wv*16+16), both 16-n subtiles.
// ---------------------------------------------------------------------------
__global__ __launch_bounds__(256) void score_softmax_assign(
    const float* __restrict__ x, const float* __restrict__ w,
    unsigned short* __restrict__ assign, float* __restrict__ asum) {
  __shared__ float s[64 * 33];   // scores [k][n-local], pad 33
  __shared__ float red[8][32];
  __shared__ float scol[32];

  const int t = threadIdx.x;
  const int b = blockIdx.y;
  const int n0 = blockIdx.x * 32;
  const int wv = t >> 6;
  const int lane = t & 63;
  const int q = lane >> 4;
  const int m = lane & 15;

  f32x4 acc0 = {0.f, 0.f, 0.f, 0.f};
  f32x4 acc1 = {0.f, 0.f, 0.f, 0.f};

  // B-operand column base: x[b][.][n0 + m] (+16 for second subtile)
  const float* xb = x + (size_t)b * Dv * Nv + n0 + m;
  // A-operand row base: w[wv*16+m][q*8 ...]
  const float* wp = w + (size_t)(wv * 16 + m) * Dv + q * 8;

#pragma unroll 2
  for (int d0 = 0; d0 < Dv; d0 += 32) {
    // A-frag: 8 consecutive d from w row (32B)
    float4 wa = *(const float4*)(wp + d0);
    float4 wc = *(const float4*)(wp + d0 + 4);
    // B-frags: strided column reads (each instr covers 4 rows x 64B segments)
    float b0[8], b1[8];
#pragma unroll
    for (int j = 0; j < 8; j++) {
      const float* rp = xb + (size_t)(d0 + q * 8 + j) * Nv;
      b0[j] = rp[0];
      b1[j] = rp[16];
    }
    bf16x8 af, bf0, bf1;
    af[0] = (short)f2b(wa.x); af[1] = (short)f2b(wa.y);
    af[2] = (short)f2b(wa.z); af[3] = (short)f2b(wa.w);
    af[4] = (short)f2b(wc.x); af[5] = (short)f2b(wc.y);
    af[6] = (short)f2b(wc.z); af[7] = (short)f2b(wc.w);
#pragma unroll
    for (int j = 0; j < 8; j++) { bf0[j] = (short)f2b(b0[j]); bf1[j] = (short)f2b(b1[j]); }
    acc0 = __builtin_amdgcn_mfma_f32_16x16x32_bf16(af, bf0, acc0, 0, 0, 0);
    acc1 = __builtin_amdgcn_mfma_f32_16x16x32_bf16(af, bf1, acc1, 0, 0, 0);
  }

  // scores -> LDS: C/D layout col(N)=lane&15, row(M)=q*4+r
#pragma unroll
  for (int r = 0; r < 4; r++) {
    s[(wv * 16 + q * 4 + r) * 33 + m] = acc0[r];
    s[(wv * 16 + q * 4 + r) * 33 + 16 + m] = acc1[r];
  }
  __syncthreads();

  // softmax over k (64) per column; 8 threads per column (g = k-group of 8)
  const int c = t & 31;
  const int g = t >> 5;
  float mx = -1e30f;
#pragma unroll
  for (int kk = 0; kk < 8; kk++) mx = fmaxf(mx, s[(g * 8 + kk) * 33 + c]);
  red[g][c] = mx;
  __syncthreads();
  float mcol = red[0][c];
#pragma unroll
  for (int i = 1; i < 8; i++) mcol = fmaxf(mcol, red[i][c]);
  float ps = 0.f;
#pragma unroll
  for (int kk = 0; kk < 8; kk++) {
    float e = __expf(s[(g * 8 + kk) * 33 + c] - mcol);
    s[(g * 8 + kk) * 33 + c] = e;
    ps += e;
  }
  __syncthreads();   // all mcol reads of red done before overwrite
  red[g][c] = ps;
  __syncthreads();
  float sum = red[0][c];
#pragma unroll
  for (int i = 1; i < 8; i++) sum += red[i][c];
  if (g == 0) scol[c] = 1.0f / sum;
  __syncthreads();

  // per-(b,k) partial column sums -> atomicAdd
  if (t < 64) {
    float sk = 0.f;
#pragma unroll
    for (int c2 = 0; c2 < 32; c2++) sk += s[t * 33 + c2] * scol[c2];
    atomicAdd(&asum[b * Kv + t], sk);
  }

  // write assign as bf16 (packed pairs): 64k x 16 pairs
  unsigned short* ab = assign + (size_t)b * Kv * Nv + n0;
#pragma unroll
  for (int r2 = 0; r2 < 4; r2++) {
    int idx = r2 * 256 + t;            // 0..1023 over 64k x 16 n-pairs
    int k = idx >> 4;
    int np = (idx & 15) * 2;
    unsigned pack = (unsigned)f2b(s[k * 33 + np] * scol[np]) |
                    ((unsigned)f2b(s[k * 33 + np + 1] * scol[np + 1]) << 16);
    *(unsigned*)&ab[(size_t)k * Nv + np] = pack;
  }
}

// ---------------------------------------------------------------------------
// Kernel B: vlad[b,d,k] = sum_n x*assign - centers*asum via bf16 MFMA.
// LDS-free, barrier-free; fuses colsq (sum over d of vlad^2) via atomics.
// Grid (D/16, B) = (32, 32) = 1024 blocks, 256 threads.
// Wave wv: d-rows [d0, d0+16), k-cols [wv*16, wv*16+16).
// ---------------------------------------------------------------------------
__global__ __launch_bounds__(256) void vlad_mfma(
    const float* __restrict__ x, const unsigned short* __restrict__ assign,
    const float* __restrict__ centers, const float* __restrict__ asum,
    float* __restrict__ vlad, float* __restrict__ colsq) {
  const int t = threadIdx.x;
  const int b = blockIdx.y;
  const int d0 = blockIdx.x * 16;
  const int wv = t >> 6;
  const int lane = t & 63;
  const int q = lane >> 4;
  const int m = lane & 15;

  f32x4 acc0 = {0.f, 0.f, 0.f, 0.f};
  f32x4 acc1 = {0.f, 0.f, 0.f, 0.f};

  const float* xp = x + ((size_t)b * Dv + d0 + m) * Nv + q * 8;
  const unsigned short* ap = assign + ((size_t)b * Kv + wv * 16 + m) * Nv + q * 8;

#pragma unroll 2
  for (int n = 0; n < Nv; n += 64) {
    float4 xa0 = *(const float4*)(xp + n);
    float4 xc0 = *(const float4*)(xp + n + 4);
    bf16x8 bfa = *(const bf16x8*)(ap + n);
    float4 xa1 = *(const float4*)(xp + n + 32);
    float4 xc1 = *(const float4*)(xp + n + 36);
    bf16x8 bfb = *(const bf16x8*)(ap + n + 32);
    bf16x8 af0, af1;
    af0[0] = (short)f2b(xa0.x); af0[1] = (short)f2b(xa0.y);
    af0[2] = (short)f2b(xa0.z); af0[3] = (short)f2b(xa0.w);
    af0[4] = (short)f2b(xc0.x); af0[5] = (short)f2b(xc0.y);
    af0[6] = (short)f2b(xc0.z); af0[7] = (short)f2b(xc0.w);
    af1[0] = (short)f2b(xa1.x); af1[1] = (short)f2b(xa1.y);
    af1[2] = (short)f2b(xa1.z); af1[3] = (short)f2b(xa1.w);
    af1[4] = (short)f2b(xc1.x); af1[5] = (short)f2b(xc1.y);
    af1[6] = (short)f2b(xc1.z); af1[7] = (short)f2b(xc1.w);
    acc0 = __builtin_amdgcn_mfma_f32_16x16x32_bf16(af0, bfa, acc0, 0, 0, 0);
    acc1 = __builtin_amdgcn_mfma_f32_16x16x32_bf16(af1, bfb, acc1, 0, 0, 0);
  }

  const int k = wv * 16 + m;
  const float as = asum[b * Kv + k];
  float ss = 0.f;
#pragma unroll
  for (int r = 0; r < 4; r++) {
    int d = d0 + q * 4 + r;
    float v = (acc0[r] + acc1[r]) - centers[d * Kv + k] * as;
    vlad[((size_t)b * Dv + d) * Kv + k] = v;
    ss = fmaf(v, v, ss);
  }
  // reduce ss across the 4 q-groups that share this k (lanes q*16+m)
  ss += __shfl_xor(ss, 16);
  ss += __shfl_xor(ss, 32);
  if (q == 0) atomicAdd(&colsq[b * Kv + k], ss);
}

// ---------------------------------------------------------------------------
// Kernel D: out = vlad * colscale[b,k] * bscale[b]; scales computed in-block
// from colsq (256B read + rsqrt per block). Grid B*D*K/256 = 4096.
// ---------------------------------------------------------------------------
__global__ __launch_bounds__(256) void scale_kernel(
    const float* __restrict__ vlad, const float* __restrict__ colsq,
    float* __restrict__ out) {
  const int t = threadIdx.x;
  const size_t i = (size_t)blockIdx.x * 256 + t;
  const int b = (int)(i >> 15);  // D*K = 32768 per b
  __shared__ float scs[64];
  __shared__ float bsh;
  if (t < 64) {
    float tot = colsq[b * Kv + t];
    float sc = 1.0f / fmaxf(sqrtf(tot), EPSv);
    scs[t] = sc;
    float contrib = tot * sc * sc;
#pragma unroll
    for (int off = 32; off > 0; off >>= 1) contrib += __shfl_down(contrib, off);
    if (t == 0) bsh = 1.0f / fmaxf(sqrtf(contrib), EPSv);
  }
  __syncthreads();
  out[i] = vlad[i] * scs[i & 63] * bsh;
}

extern "C" void kernel_launch(void* const* d_in, const int* in_sizes, int n_in,
                              void* d_out, int out_size, void* d_ws, size_t ws_size,
                              hipStream_t stream) {
  const float* x = (const float*)d_in[0];        // [B, D, N]
  const float* w = (const float*)d_in[1];        // [K, D]
  const float* centers = (const float*)d_in[2];  // [D, K]
  float* out = (float*)d_out;                    // [B, D*K]

  char* ws = (char*)d_ws;
  unsigned short* assign = (unsigned short*)ws;  // B*K*N bf16 = 4 MB
  float* vlad = (float*)(ws + 4194304);          // B*D*K fp32 = 4 MB
  float* asum = (float*)(ws + 8388608);          // B*K
  float* colsq = asum + Bv * Kv;                 // B*K (contiguous with asum)

  hipMemsetAsync(asum, 0, (size_t)2 * Bv * Kv * sizeof(float), stream);

  score_softmax_assign<<<dim3(Nv / 32, Bv), 256, 0, stream>>>(x, w, assign, asum);
  vlad_mfma<<<dim3(Dv / 16, Bv), 256, 0, stream>>>(x, assign, centers, asum, vlad, colsq);
  scale_kernel<<<(Bv * Dv * Kv) / 256, 256, 0, stream>>>(vlad, colsq, out);
}